// Round 3
// baseline (761.597 us; speedup 1.0000x reference)
//
#include <hip/hip_runtime.h>
#include <type_traits>
#include <utility>
#include <stdint.h>
#include <stddef.h>

#define TOKENS 8192
#define CDIM 2048
#define FDIM 8192
#define EPSV 1.1920929e-07f

typedef __attribute__((ext_vector_type(8))) short short8;
typedef __attribute__((ext_vector_type(8))) __bf16 bf16x8;
typedef __attribute__((ext_vector_type(4))) float floatx4;
typedef __attribute__((ext_vector_type(4))) float f32x4;
typedef __attribute__((ext_vector_type(2))) unsigned int u32x2;

// Detect which operand typing this clang uses for the gfx950 bf16 MFMA builtin.
template <typename V, typename = void> struct CanMfma : std::false_type {};
template <typename V>
struct CanMfma<V, std::void_t<decltype(__builtin_amdgcn_mfma_f32_16x16x32_bf16(
    std::declval<V>(), std::declval<V>(), std::declval<floatx4>(), 0, 0, 0))>>
    : std::true_type {};
using frag_t = std::conditional_t<CanMfma<short8>::value, short8, bf16x8>;

__device__ __forceinline__ floatx4 mfma_bf16(frag_t a, frag_t b, floatx4 c) {
    return __builtin_amdgcn_mfma_f32_16x16x32_bf16(a, b, c, 0, 0, 0);
}

// round-to-nearest-even f32 -> bf16
__device__ __forceinline__ unsigned short f2bf(float f) {
    unsigned int u = __float_as_uint(f);
    u += 0x7fffu + ((u >> 16) & 1u);
    return (unsigned short)(u >> 16);
}

__global__ void zero_kernel(int* p) { if (threadIdx.x == 0) *p = 0; }

// Convert both weight matrices fp32 -> bf16 in one launch.
// NT stores: weights are consumed by the GEMMs next dispatch; leaving them
// dirty in the writing XCD's L2 forces cross-XCD snoop/flush on every
// consumer staging load (per-XCD L2s are not cross-coherent). nt pushes them
// to L3/HBM clean.
__global__ __launch_bounds__(256) void cvt2_kernel(
    const float* __restrict__ s1, unsigned short* __restrict__ d1, int n1,
    const float* __restrict__ s2, unsigned short* __restrict__ d2, int n2)
{
    int i = blockIdx.x * 256 + threadIdx.x;
    const float4* s; ushort4* d;
    if (i < n1) { s = (const float4*)s1; d = (ushort4*)d1; }
    else if (i < n1 + n2) { s = (const float4*)s2; d = (ushort4*)d2; i -= n1; }
    else return;
    float4 v = s[i];
    u32x2 w;
    w.x = (unsigned)f2bf(v.x) | ((unsigned)f2bf(v.y) << 16);
    w.y = (unsigned)f2bf(v.z) | ((unsigned)f2bf(v.w) << 16);
    __builtin_nontemporal_store(w, (u32x2*)&d[i]);
}

// Per token: router logit, sigmoid mask, RMSNorm; compact selected tokens into
// Xn (bf16). UNSELECTED tokens get out = x (residual base) here; SELECTED
// tokens are fully written by GEMM2 (out = x + mask*mlp), so skip them.
// All producer->consumer stores are non-temporal (clean hand-off via L3).
__global__ __launch_bounds__(256) void router_kernel(
    const float* __restrict__ x, const float* __restrict__ wr,
    float* __restrict__ out, unsigned short* __restrict__ Xn,
    int* __restrict__ idx, float* __restrict__ mv, int* __restrict__ cnt)
{
    const int token = blockIdx.x;
    const int tid = threadIdx.x;
    const float4* xr = (const float4*)(x + (size_t)token * CDIM);
    const float4* w4 = (const float4*)wr;
    float4 a0 = xr[tid];
    float4 a1 = xr[tid + 256];
    float4 b0 = w4[tid];
    float4 b1 = w4[tid + 256];
    float ss = a0.x*a0.x + a0.y*a0.y + a0.z*a0.z + a0.w*a0.w
             + a1.x*a1.x + a1.y*a1.y + a1.z*a1.z + a1.w*a1.w;
    float dt = a0.x*b0.x + a0.y*b0.y + a0.z*b0.z + a0.w*b0.w
             + a1.x*b1.x + a1.y*b1.y + a1.z*b1.z + a1.w*b1.w;
    #pragma unroll
    for (int off = 32; off > 0; off >>= 1) {
        ss += __shfl_down(ss, off);
        dt += __shfl_down(dt, off);
    }
    __shared__ float red_ss[4], red_dt[4];
    __shared__ float s_rms;
    __shared__ int s_pos;
    const int wave = tid >> 6;
    if ((tid & 63) == 0) { red_ss[wave] = ss; red_dt[wave] = dt; }
    __syncthreads();
    if (tid == 0) {
        float S = red_ss[0] + red_ss[1] + red_ss[2] + red_ss[3];
        float D = red_dt[0] + red_dt[1] + red_dt[2] + red_dt[3];
        float prob = 1.0f / (1.0f + expf(-D));
        s_rms = 1.0f / sqrtf(S * (1.0f / (float)CDIM) + EPSV);
        int pos = -1;
        if (prob > 0.5f) {
            pos = atomicAdd(cnt, 1);
            idx[pos] = token;
            mv[pos] = (1.0f + prob) - prob;  // replicate STE mask_i rounding exactly
        }
        s_pos = pos;
    }
    __syncthreads();
    const float rms = s_rms;
    const int pos = s_pos;
    float* op = out + (size_t)token * CDIM;
    if (pos < 0) {
        // residual base only for unselected tokens
        f32x4 r0 = {a0.x, a0.y, a0.z, a0.w};
        f32x4 r1 = {a1.x, a1.y, a1.z, a1.w};
        __builtin_nontemporal_store(r0, (f32x4*)(op + tid * 4));
        __builtin_nontemporal_store(r1, (f32x4*)(op + (tid + 256) * 4));
    } else {
        unsigned short* xp = Xn + (size_t)pos * CDIM;
        u32x2 w;
        w.x = (unsigned)f2bf(a0.x * rms) | ((unsigned)f2bf(a0.y * rms) << 16);
        w.y = (unsigned)f2bf(a0.z * rms) | ((unsigned)f2bf(a0.w * rms) << 16);
        __builtin_nontemporal_store(w, (u32x2*)(xp + tid * 4));
        w.x = (unsigned)f2bf(a1.x * rms) | ((unsigned)f2bf(a1.y * rms) << 16);
        w.y = (unsigned)f2bf(a1.z * rms) | ((unsigned)f2bf(a1.w * rms) << 16);
        __builtin_nontemporal_store(w, (u32x2*)(xp + (tid + 256) * 4));
    }
}

// C[m][n] = sum_k A[m][k]*B[n][k], A:[M][K] bf16 (compacted rows), B:[N][K] bf16.
// 128x128 tile, BK=64, 4 waves 2x2, 4x4 MFMA 16x16x32; global_load_lds(16B)
// staging with XOR swizzle on the GLOBAL address side. (Round-0 structure =
// measured-best; rounds 1-2 proved the K-loop schedule is NOT the limiter.)
//
// 8x8 SUPERTILE raster, m-fastest (round-0 scheme, measured-better than rect).
// MODE 1: Hout[m][n] = bf16(relu(acc)^2), NT store (clean hand-off to GEMM2).
// MODE 2 (KSPLIT=1, no atomics): out[token][n] = x[token][n] + scale*acc —
// clean read of input x, NT store of final out. Each output owned by exactly
// one block.
template <int K, int MODE, int LDO, int KSPLIT>
__global__ __launch_bounds__(256) void gemm_bt(
    const unsigned short* __restrict__ A,
    const unsigned short* __restrict__ B,
    unsigned short* __restrict__ Hout,
    float* __restrict__ out,
    const float* __restrict__ xin,
    const int* __restrict__ idx,
    const float* __restrict__ mv,
    const int* __restrict__ cntp)
{
    const int cnt = *cntp;
    // supertile swizzle (gridDim.x == 64 m-panels for both GEMMs)
    const int bid = blockIdx.y * 64 + blockIdx.x;
    const int s = bid >> 6;          // supertile id
    const int w = bid & 63;          // position within 8x8 supertile
    const int mi = (s & 7) * 8 + (w & 7);    // Mp=64 -> 8 supertile rows, m-fastest
    const int ni = (s >> 3) * 8 + (w >> 3);
    const int m0 = mi * 128;
    if (m0 >= cnt) return;
    const int n0 = ni * 128;
    const int k0 = (int)blockIdx.z * (K / KSPLIT);   // element offset in k

    __shared__ alignas(16) unsigned short lA[128 * 64];
    __shared__ alignas(16) unsigned short lB[128 * 64];

    const int tid = threadIdx.x;
    const int wave = tid >> 6;
    const int lane = tid & 63;
    const int wm = (wave >> 1) * 64;
    const int wn = (wave & 1) * 64;
    const int quad = lane >> 4;
    const int l16 = lane & 15;

    // staging: wave w, issue p covers rows p*32+w*8 .. +8; lane i -> row +i/8,
    // global 16B chunk (i&7)^(i/8) (swizzle), LDS chunk i&7 (hardware lane order)
    const int srow = lane >> 3;
    const int schunk = (lane & 7) ^ srow;

    const unsigned short* ap[4];
    const unsigned short* bp[4];
    #pragma unroll
    for (int p = 0; p < 4; ++p) {
        const int r = p * 32 + wave * 8 + srow;
        ap[p] = A + (size_t)(m0 + r) * K + k0 + schunk * 8;
        bp[p] = B + (size_t)(n0 + r) * K + k0 + schunk * 8;
    }

    floatx4 acc[4][4] = {};

    for (int kt = 0; kt < K / (64 * KSPLIT); ++kt) {
        #pragma unroll
        for (int p = 0; p < 4; ++p) {
            __builtin_amdgcn_global_load_lds(
                (__attribute__((address_space(1))) void*)ap[p],
                (__attribute__((address_space(3))) void*)&lA[(p * 32 + wave * 8) * 64],
                16, 0, 0);
            __builtin_amdgcn_global_load_lds(
                (__attribute__((address_space(1))) void*)bp[p],
                (__attribute__((address_space(3))) void*)&lB[(p * 32 + wave * 8) * 64],
                16, 0, 0);
            ap[p] += 64;
            bp[p] += 64;
        }
        __syncthreads();  // drains vmcnt before LDS reads
        #pragma unroll
        for (int st = 0; st < 2; ++st) {
            frag_t af[4], bfv[4];
            #pragma unroll
            for (int t = 0; t < 4; ++t) {
                const int ra = wm + t * 16 + l16;
                const int ca = ((st * 4 + quad) ^ (ra & 7)) * 8;
                af[t] = *(const frag_t*)&lA[ra * 64 + ca];
                const int rb = wn + t * 16 + l16;
                const int cb = ((st * 4 + quad) ^ (rb & 7)) * 8;
                bfv[t] = *(const frag_t*)&lB[rb * 64 + cb];
            }
            #pragma unroll
            for (int tm = 0; tm < 4; ++tm)
                #pragma unroll
                for (int tn = 0; tn < 4; ++tn)
                    acc[tm][tn] = mfma_bf16(af[tm], bfv[tn], acc[tm][tn]);
        }
        __syncthreads();
    }

    // C/D layout (verified m89/m91): col(n) = lane&15, row(m) = quad*4 + reg
    if (MODE == 1) {
        #pragma unroll
        for (int tm = 0; tm < 4; ++tm) {
            const int gm = m0 + wm + tm * 16 + quad * 4;
            #pragma unroll
            for (int tn = 0; tn < 4; ++tn) {
                const int gn = n0 + wn + tn * 16 + l16;
                #pragma unroll
                for (int v = 0; v < 4; ++v) {
                    float h = fmaxf(acc[tm][tn][v], 0.0f);  // fmax eats NaN pad rows too
                    unsigned short hb = f2bf(h * h);
                    __builtin_nontemporal_store(hb, &Hout[(size_t)(gm + v) * LDO + gn]);
                }
            }
        }
    } else {
        #pragma unroll
        for (int tm = 0; tm < 4; ++tm) {
            const int gmb = m0 + wm + tm * 16 + quad * 4;
            #pragma unroll
            for (int v = 0; v < 4; ++v) {
                const int gm = gmb + v;
                if (gm < cnt) {  // never read poisoned idx/mv beyond cnt
                    const int token = idx[gm];
                    const float scale = mv[gm];
                    const float* xrow = xin + (size_t)token * LDO;
                    float* orow = out + (size_t)token * LDO;
                    #pragma unroll
                    for (int tn = 0; tn < 4; ++tn) {
                        const int gn = n0 + wn + tn * 16 + l16;
                        float r = xrow[gn] + scale * acc[tm][tn][v];
                        __builtin_nontemporal_store(r, &orow[gn]);
                    }
                }
            }
        }
    }
}

extern "C" void kernel_launch(void* const* d_in, const int* in_sizes, int n_in,
                              void* d_out, int out_size, void* d_ws, size_t ws_size,
                              hipStream_t stream)
{
    const float* x   = (const float*)d_in[0];
    const float* wfc = (const float*)d_in[1];
    const float* wpr = (const float*)d_in[2];
    const float* wrt = (const float*)d_in[3];
    float* out = (float*)d_out;

    // ws layout (bytes): [cnt 256][idx 32K][mv 32K][Xn 32M][Wfc 32M][Wpr 32M][H 128M]
    char* ws = (char*)d_ws;
    int*   cnt = (int*)ws;
    int*   idx = (int*)(ws + 256);
    float* mv  = (float*)(ws + 256 + 32768);
    unsigned short* Xn  = (unsigned short*)(ws + 65792);
    unsigned short* Wfc = (unsigned short*)(ws + 65792 + 33554432ULL);
    unsigned short* Wpr = (unsigned short*)(ws + 65792 + 67108864ULL);
    unsigned short* H   = (unsigned short*)(ws + 65792 + 100663296ULL);

    const int n4 = FDIM * CDIM / 4;  // float4 count per weight matrix
    zero_kernel<<<1, 64, 0, stream>>>(cnt);
    cvt2_kernel<<<(2 * n4 + 255) / 256, 256, 0, stream>>>(wfc, Wfc, n4, wpr, Wpr, n4);
    router_kernel<<<TOKENS, 256, 0, stream>>>(x, wrt, out, Xn, idx, mv, cnt);
    // GEMM1: H[m][f] = relu(Xn @ Wfc^T)^2, M=cnt (<=8192), N=8192, K=2048
    gemm_bt<CDIM, 1, FDIM, 1><<<dim3(64, FDIM / 128), 256, 0, stream>>>(
        Xn, Wfc, H, nullptr, nullptr, nullptr, nullptr, cnt);
    // GEMM2: out[token][c] = x[token][c] + mask_i*(H @ Wpr^T), M=cnt, N=2048,
    // K=8192, KSPLIT=1 (each output owned by one block -> plain NT stores)
    gemm_bt<FDIM, 2, CDIM, 1><<<dim3(64, CDIM / 128), 256, 0, stream>>>(
        H, Wpr, nullptr, out, x, idx, mv, cnt);
}

// Round 4
// 753.482 us; speedup vs baseline: 1.0108x; 1.0108x over previous
//
#include <hip/hip_runtime.h>
#include <type_traits>
#include <utility>
#include <stdint.h>
#include <stddef.h>

#define TOKENS 8192
#define CDIM 2048
#define FDIM 8192
#define EPSV 1.1920929e-07f

typedef __attribute__((ext_vector_type(8))) short short8;
typedef __attribute__((ext_vector_type(8))) __bf16 bf16x8;
typedef __attribute__((ext_vector_type(4))) float floatx4;
typedef __attribute__((ext_vector_type(4))) float f32x4;
typedef __attribute__((ext_vector_type(2))) unsigned int u32x2;

// Detect which operand typing this clang uses for the gfx950 bf16 MFMA builtin.
template <typename V, typename = void> struct CanMfma : std::false_type {};
template <typename V>
struct CanMfma<V, std::void_t<decltype(__builtin_amdgcn_mfma_f32_16x16x32_bf16(
    std::declval<V>(), std::declval<V>(), std::declval<floatx4>(), 0, 0, 0))>>
    : std::true_type {};
using frag_t = std::conditional_t<CanMfma<short8>::value, short8, bf16x8>;

__device__ __forceinline__ floatx4 mfma_bf16(frag_t a, frag_t b, floatx4 c) {
    return __builtin_amdgcn_mfma_f32_16x16x32_bf16(a, b, c, 0, 0, 0);
}

// round-to-nearest-even f32 -> bf16
__device__ __forceinline__ unsigned short f2bf(float f) {
    unsigned int u = __float_as_uint(f);
    u += 0x7fffu + ((u >> 16) & 1u);
    return (unsigned short)(u >> 16);
}

__global__ void zero_kernel(int* p) { if (threadIdx.x == 0) *p = 0; }

// ---------------------------------------------------------------------------
// PACKED TILE LAYOUT (the round-4 fix):
// All GEMM operands are stored as [panel(128 rows)][ktile(64 cols)] tile-chunks
// of 16 KB, contiguous, with the XOR chunk swizzle BAKED IN:
//   element (row_global=n, k) lives at
//     u16 index ((n>>7)*PK + (k>>6))*8192 + ((n&127)*8 + (((k>>3)&7) ^ (n&7)))*8 + (k&7)
//   where PK = K/64.
// GEMM staging then reads each tile as a single fully-CONTIGUOUS 16 KB stream
// (lane i -> base + i*16B): ideal HBM bursts across all channels. The previous
// row-major layout made every staging instruction a 128B read at 4KB/16KB
// power-of-two stride -> HBM channel imbalance, measured ~0.85 TB/s effective
// (dur == hbm_bytes/0.85TB/s across rounds 0-3 regardless of schedule).
// ---------------------------------------------------------------------------

// Convert both weight matrices fp32 -> packed-swizzled bf16 in one launch.
// Wfc: rows=FDIM, K=CDIM (PK=32). Wpr: rows=CDIM, K=FDIM (PK=128).
__global__ __launch_bounds__(256) void cvt2_kernel(
    const float* __restrict__ s1, unsigned short* __restrict__ d1,
    const float* __restrict__ s2, unsigned short* __restrict__ d2)
{
    const int NC1 = FDIM * (CDIM / 8);   // 16B chunks in matrix 1
    int i = blockIdx.x * 256 + threadIdx.x;
    const float* src; unsigned short* dst;
    int n, t, PK, K8;
    if (i < NC1) { src = s1; dst = d1; n = i >> 8; t = i & 255; PK = 32; K8 = 256; }
    else { i -= NC1; src = s2; dst = d2; n = i >> 10; t = i & 1023; PK = 128; K8 = 1024; }
    const int kt = t >> 3, q8 = t & 7;
    const int r = n & 127, ni = n >> 7;
    const float4* sp = (const float4*)src + ((size_t)n * K8 + t) * 2;
    float4 v0 = sp[0], v1 = sp[1];
    short8 o;
    o[0] = (short)f2bf(v0.x); o[1] = (short)f2bf(v0.y);
    o[2] = (short)f2bf(v0.z); o[3] = (short)f2bf(v0.w);
    o[4] = (short)f2bf(v1.x); o[5] = (short)f2bf(v1.y);
    o[6] = (short)f2bf(v1.z); o[7] = (short)f2bf(v1.w);
    size_t di = (((size_t)ni * PK + kt) * 128 + r) * 64 + (size_t)((q8 ^ (r & 7)) << 3);
    __builtin_nontemporal_store(o, (short8*)(dst + di));
}

// Per token: router logit, sigmoid mask, RMSNorm; compact selected tokens into
// Xn (bf16, PACKED layout, PK=32). UNSELECTED tokens get out = x here;
// SELECTED tokens are fully written by GEMM2 (out = x + mask*mlp).
__global__ __launch_bounds__(256) void router_kernel(
    const float* __restrict__ x, const float* __restrict__ wr,
    float* __restrict__ out, unsigned short* __restrict__ Xn,
    int* __restrict__ idx, float* __restrict__ mv, int* __restrict__ cnt)
{
    const int token = blockIdx.x;
    const int tid = threadIdx.x;
    const float4* xr = (const float4*)(x + (size_t)token * CDIM);
    const float4* w4 = (const float4*)wr;
    // thread tid owns k = tid*8 .. tid*8+7  (one packed 16B chunk)
    float4 a0 = xr[2 * tid];
    float4 a1 = xr[2 * tid + 1];
    float4 b0 = w4[2 * tid];
    float4 b1 = w4[2 * tid + 1];
    float ss = a0.x*a0.x + a0.y*a0.y + a0.z*a0.z + a0.w*a0.w
             + a1.x*a1.x + a1.y*a1.y + a1.z*a1.z + a1.w*a1.w;
    float dt = a0.x*b0.x + a0.y*b0.y + a0.z*b0.z + a0.w*b0.w
             + a1.x*b1.x + a1.y*b1.y + a1.z*b1.z + a1.w*b1.w;
    #pragma unroll
    for (int off = 32; off > 0; off >>= 1) {
        ss += __shfl_down(ss, off);
        dt += __shfl_down(dt, off);
    }
    __shared__ float red_ss[4], red_dt[4];
    __shared__ float s_rms;
    __shared__ int s_pos;
    const int wave = tid >> 6;
    if ((tid & 63) == 0) { red_ss[wave] = ss; red_dt[wave] = dt; }
    __syncthreads();
    if (tid == 0) {
        float S = red_ss[0] + red_ss[1] + red_ss[2] + red_ss[3];
        float D = red_dt[0] + red_dt[1] + red_dt[2] + red_dt[3];
        float prob = 1.0f / (1.0f + expf(-D));
        s_rms = 1.0f / sqrtf(S * (1.0f / (float)CDIM) + EPSV);
        int pos = -1;
        if (prob > 0.5f) {
            pos = atomicAdd(cnt, 1);
            idx[pos] = token;
            mv[pos] = (1.0f + prob) - prob;  // replicate STE mask_i rounding exactly
        }
        s_pos = pos;
    }
    __syncthreads();
    const float rms = s_rms;
    const int pos = s_pos;
    float* op = out + (size_t)token * CDIM;
    if (pos < 0) {
        // residual base only for unselected tokens
        f32x4 r0 = {a0.x, a0.y, a0.z, a0.w};
        f32x4 r1 = {a1.x, a1.y, a1.z, a1.w};
        __builtin_nontemporal_store(r0, (f32x4*)(op + tid * 8));
        __builtin_nontemporal_store(r1, (f32x4*)(op + tid * 8 + 4));
    } else {
        // packed-swizzled write: chunk t=tid of compacted row pos
        const int kt = tid >> 3, q8 = tid & 7;
        const int r = pos & 127, mi = pos >> 7;
        short8 o;
        o[0] = (short)f2bf(a0.x * rms); o[1] = (short)f2bf(a0.y * rms);
        o[2] = (short)f2bf(a0.z * rms); o[3] = (short)f2bf(a0.w * rms);
        o[4] = (short)f2bf(a1.x * rms); o[5] = (short)f2bf(a1.y * rms);
        o[6] = (short)f2bf(a1.z * rms); o[7] = (short)f2bf(a1.w * rms);
        size_t di = (((size_t)mi * 32 + kt) * 128 + r) * 64 + (size_t)((q8 ^ (r & 7)) << 3);
        __builtin_nontemporal_store(o, (short8*)(Xn + di));
    }
}

// C[m][n] = sum_k A[m][k]*B[n][k]; A,B in PACKED tile layout (see above).
// 128x128 tile, BK=64, 4 waves 2x2, 4x4 MFMA 16x16x32; global_load_lds(16B)
// staging is now FULLY CONTIGUOUS per tile (16 KB sequential per operand per
// K-step). LDS content and fragment-read side are byte-identical to the
// round-0 kernel (swizzle pre-baked in the packed layout; 0 bank conflicts).
//
// 8x8 SUPERTILE raster, m-fastest (measured-best).
// MODE 1: Hout = bf16(relu(acc)^2) written in PACKED layout for GEMM2's A
//         (tile-local stores: the block's whole H output lands in 2 contiguous
//         16KB chunks per tn-range instead of 16KB-strided 32B pieces).
// MODE 2: out[token][n] = x[token][n] + scale*acc (KSPLIT=1, no atomics).
template <int K, int MODE, int LDO, int KSPLIT>
__global__ __launch_bounds__(256) void gemm_bt(
    const unsigned short* __restrict__ A,
    const unsigned short* __restrict__ B,
    unsigned short* __restrict__ Hout,
    float* __restrict__ out,
    const float* __restrict__ xin,
    const int* __restrict__ idx,
    const float* __restrict__ mv,
    const int* __restrict__ cntp)
{
    const int cnt = *cntp;
    // supertile swizzle (gridDim.x == 64 m-panels for both GEMMs)
    const int bid = blockIdx.y * 64 + blockIdx.x;
    const int s = bid >> 6;          // supertile id
    const int w = bid & 63;          // position within 8x8 supertile
    const int mi = (s & 7) * 8 + (w & 7);    // m-fastest
    const int ni = (s >> 3) * 8 + (w >> 3);
    const int m0 = mi * 128;
    if (m0 >= cnt) return;
    const int n0 = ni * 128;
    const int k0 = (int)blockIdx.z * (K / KSPLIT);   // element offset in k

    __shared__ alignas(16) unsigned short lA[128 * 64];
    __shared__ alignas(16) unsigned short lB[128 * 64];

    const int tid = threadIdx.x;
    const int wave = tid >> 6;
    const int lane = tid & 63;
    const int wm = (wave >> 1) * 64;
    const int wn = (wave & 1) * 64;
    const int quad = lane >> 4;
    const int l16 = lane & 15;

    constexpr int PK = K / 64;
    // contiguous staging: thread tid reads 16B at tile_base + tid*16B (+p*4KB)
    const unsigned short* aq = A + ((size_t)mi * PK + (k0 >> 6)) * 8192 + (size_t)tid * 8;
    const unsigned short* bq = B + ((size_t)ni * PK + (k0 >> 6)) * 8192 + (size_t)tid * 8;

    floatx4 acc[4][4] = {};

    for (int kt = 0; kt < K / (64 * KSPLIT); ++kt) {
        #pragma unroll
        for (int p = 0; p < 4; ++p) {
            __builtin_amdgcn_global_load_lds(
                (__attribute__((address_space(1))) void*)(aq + p * 2048),
                (__attribute__((address_space(3))) void*)&lA[(p * 256 + wave * 64) * 8],
                16, 0, 0);
            __builtin_amdgcn_global_load_lds(
                (__attribute__((address_space(1))) void*)(bq + p * 2048),
                (__attribute__((address_space(3))) void*)&lB[(p * 256 + wave * 64) * 8],
                16, 0, 0);
        }
        aq += 8192;
        bq += 8192;
        __syncthreads();  // drains vmcnt before LDS reads
        #pragma unroll
        for (int st = 0; st < 2; ++st) {
            frag_t af[4], bfv[4];
            #pragma unroll
            for (int t = 0; t < 4; ++t) {
                const int ra = wm + t * 16 + l16;
                const int ca = ((st * 4 + quad) ^ (ra & 7)) * 8;
                af[t] = *(const frag_t*)&lA[ra * 64 + ca];
                const int rb = wn + t * 16 + l16;
                const int cb = ((st * 4 + quad) ^ (rb & 7)) * 8;
                bfv[t] = *(const frag_t*)&lB[rb * 64 + cb];
            }
            #pragma unroll
            for (int tm = 0; tm < 4; ++tm)
                #pragma unroll
                for (int tn = 0; tn < 4; ++tn)
                    acc[tm][tn] = mfma_bf16(af[tm], bfv[tn], acc[tm][tn]);
        }
        __syncthreads();
    }

    // C/D layout (verified m89/m91): col(n) = lane&15, row(m) = quad*4 + reg
    if (MODE == 1) {
        constexpr int PKH = LDO / 64;   // H packed with K = LDO = FDIM
        #pragma unroll
        for (int tm = 0; tm < 4; ++tm) {
            const int rbase = wm + tm * 16 + quad * 4;  // row within this m-panel
            #pragma unroll
            for (int tn = 0; tn < 4; ++tn) {
                const int gn = n0 + wn + tn * 16 + l16;
                const int kt = gn >> 6, q8 = (gn >> 3) & 7, e = gn & 7;
                #pragma unroll
                for (int v = 0; v < 4; ++v) {
                    const int r = rbase + v;
                    float h = fmaxf(acc[tm][tn][v], 0.0f);  // fmax eats NaN pad rows too
                    size_t di = (((size_t)mi * PKH + kt) * 128 + r) * 64
                              + (size_t)((q8 ^ (r & 7)) << 3) + e;
                    __builtin_nontemporal_store(f2bf(h * h), &Hout[di]);
                }
            }
        }
    } else {
        #pragma unroll
        for (int tm = 0; tm < 4; ++tm) {
            const int gmb = m0 + wm + tm * 16 + quad * 4;
            #pragma unroll
            for (int v = 0; v < 4; ++v) {
                const int gm = gmb + v;
                if (gm < cnt) {  // never read poisoned idx/mv beyond cnt
                    const int token = idx[gm];
                    const float scale = mv[gm];
                    const float* xrow = xin + (size_t)token * LDO;
                    float* orow = out + (size_t)token * LDO;
                    #pragma unroll
                    for (int tn = 0; tn < 4; ++tn) {
                        const int gn = n0 + wn + tn * 16 + l16;
                        float r = xrow[gn] + scale * acc[tm][tn][v];
                        __builtin_nontemporal_store(r, &orow[gn]);
                    }
                }
            }
        }
    }
}

extern "C" void kernel_launch(void* const* d_in, const int* in_sizes, int n_in,
                              void* d_out, int out_size, void* d_ws, size_t ws_size,
                              hipStream_t stream)
{
    const float* x   = (const float*)d_in[0];
    const float* wfc = (const float*)d_in[1];
    const float* wpr = (const float*)d_in[2];
    const float* wrt = (const float*)d_in[3];
    float* out = (float*)d_out;

    // ws layout (bytes): [cnt 256][idx 32K][mv 32K][Xn 32M][Wfc 32M][Wpr 32M][H 128M]
    char* ws = (char*)d_ws;
    int*   cnt = (int*)ws;
    int*   idx = (int*)(ws + 256);
    float* mv  = (float*)(ws + 256 + 32768);
    unsigned short* Xn  = (unsigned short*)(ws + 65792);
    unsigned short* Wfc = (unsigned short*)(ws + 65792 + 33554432ULL);
    unsigned short* Wpr = (unsigned short*)(ws + 65792 + 67108864ULL);
    unsigned short* H   = (unsigned short*)(ws + 65792 + 100663296ULL);

    // chunks: Wfc FDIM*(CDIM/8) + Wpr CDIM*(FDIM/8) = 4,194,304 -> 16384 blocks
    const int nchunks = FDIM * (CDIM / 8) + CDIM * (FDIM / 8);
    zero_kernel<<<1, 64, 0, stream>>>(cnt);
    cvt2_kernel<<<nchunks / 256, 256, 0, stream>>>(wfc, Wfc, wpr, Wpr);
    router_kernel<<<TOKENS, 256, 0, stream>>>(x, wrt, out, Xn, idx, mv, cnt);
    // GEMM1: H[m][f] = relu(Xn @ Wfc^T)^2, M=cnt (<=8192), N=8192, K=2048
    gemm_bt<CDIM, 1, FDIM, 1><<<dim3(64, FDIM / 128), 256, 0, stream>>>(
        Xn, Wfc, H, nullptr, nullptr, nullptr, nullptr, cnt);
    // GEMM2: out[token][c] = x[token][c] + mask_i*(H @ Wpr^T), M=cnt, N=2048,
    // K=8192, KSPLIT=1 (each output owned by one block -> plain NT stores)
    gemm_bt<FDIM, 2, CDIM, 1><<<dim3(64, CDIM / 128), 256, 0, stream>>>(
        H, Wpr, nullptr, out, x, idx, mv, cnt);
}

// Round 5
// 748.325 us; speedup vs baseline: 1.0177x; 1.0069x over previous
//
#include <hip/hip_runtime.h>
#include <type_traits>
#include <utility>
#include <stdint.h>
#include <stddef.h>

#define TOKENS 8192
#define CDIM 2048
#define FDIM 8192
#define EPSV 1.1920929e-07f

typedef __attribute__((ext_vector_type(8))) short short8;
typedef __attribute__((ext_vector_type(8))) __bf16 bf16x8;
typedef __attribute__((ext_vector_type(4))) float floatx4;
typedef __attribute__((ext_vector_type(4))) float f32x4;
typedef __attribute__((ext_vector_type(2))) unsigned int u32x2;

// Detect which operand typing this clang uses for the gfx950 bf16 MFMA builtin.
template <typename V, typename = void> struct CanMfma : std::false_type {};
template <typename V>
struct CanMfma<V, std::void_t<decltype(__builtin_amdgcn_mfma_f32_16x16x32_bf16(
    std::declval<V>(), std::declval<V>(), std::declval<floatx4>(), 0, 0, 0))>>
    : std::true_type {};
using frag_t = std::conditional_t<CanMfma<short8>::value, short8, bf16x8>;

__device__ __forceinline__ floatx4 mfma_bf16(frag_t a, frag_t b, floatx4 c) {
    return __builtin_amdgcn_mfma_f32_16x16x32_bf16(a, b, c, 0, 0, 0);
}

// round-to-nearest-even f32 -> bf16
__device__ __forceinline__ unsigned short f2bf(float f) {
    unsigned int u = __float_as_uint(f);
    u += 0x7fffu + ((u >> 16) & 1u);
    return (unsigned short)(u >> 16);
}

__global__ void zero_kernel(int* p) { if (threadIdx.x == 0) *p = 0; }

// ---------------------------------------------------------------------------
// PACKED TILE LAYOUT (kept from round 4): operands stored as
// [panel(128 rows)][ktile(64 cols)] 16 KB contiguous tile-chunks, XOR chunk
// swizzle baked in:
//   element (row=n, k) -> u16 index
//     ((n>>7)*PK + (k>>6))*8192 + ((n&127)*8 + (((k>>3)&7) ^ (n&7)))*8 + (k&7)
// GEMM staging reads each tile as one contiguous 16 KB stream.
// ---------------------------------------------------------------------------

// Convert both weight matrices fp32 -> packed-swizzled bf16 in one launch.
// Wfc: rows=FDIM, K=CDIM (PK=32). Wpr: rows=CDIM, K=FDIM (PK=128).
__global__ __launch_bounds__(256) void cvt2_kernel(
    const float* __restrict__ s1, unsigned short* __restrict__ d1,
    const float* __restrict__ s2, unsigned short* __restrict__ d2)
{
    const int NC1 = FDIM * (CDIM / 8);   // 16B chunks in matrix 1
    int i = blockIdx.x * 256 + threadIdx.x;
    const float* src; unsigned short* dst;
    int n, t, PK, K8;
    if (i < NC1) { src = s1; dst = d1; n = i >> 8; t = i & 255; PK = 32; K8 = 256; }
    else { i -= NC1; src = s2; dst = d2; n = i >> 10; t = i & 1023; PK = 128; K8 = 1024; }
    const int kt = t >> 3, q8 = t & 7;
    const int r = n & 127, ni = n >> 7;
    const float4* sp = (const float4*)src + ((size_t)n * K8 + t) * 2;
    float4 v0 = sp[0], v1 = sp[1];
    short8 o;
    o[0] = (short)f2bf(v0.x); o[1] = (short)f2bf(v0.y);
    o[2] = (short)f2bf(v0.z); o[3] = (short)f2bf(v0.w);
    o[4] = (short)f2bf(v1.x); o[5] = (short)f2bf(v1.y);
    o[6] = (short)f2bf(v1.z); o[7] = (short)f2bf(v1.w);
    size_t di = (((size_t)ni * PK + kt) * 128 + r) * 64 + (size_t)((q8 ^ (r & 7)) << 3);
    __builtin_nontemporal_store(o, (short8*)(dst + di));
}

// Per token: router logit, sigmoid mask, RMSNorm; compact selected tokens into
// Xn (bf16, PACKED layout, PK=32). UNSELECTED tokens get out = x here;
// SELECTED tokens are fully written by GEMM2 (out = x + mask*mlp).
__global__ __launch_bounds__(256) void router_kernel(
    const float* __restrict__ x, const float* __restrict__ wr,
    float* __restrict__ out, unsigned short* __restrict__ Xn,
    int* __restrict__ idx, float* __restrict__ mv, int* __restrict__ cnt)
{
    const int token = blockIdx.x;
    const int tid = threadIdx.x;
    const float4* xr = (const float4*)(x + (size_t)token * CDIM);
    const float4* w4 = (const float4*)wr;
    // thread tid owns k = tid*8 .. tid*8+7  (one packed 16B chunk)
    float4 a0 = xr[2 * tid];
    float4 a1 = xr[2 * tid + 1];
    float4 b0 = w4[2 * tid];
    float4 b1 = w4[2 * tid + 1];
    float ss = a0.x*a0.x + a0.y*a0.y + a0.z*a0.z + a0.w*a0.w
             + a1.x*a1.x + a1.y*a1.y + a1.z*a1.z + a1.w*a1.w;
    float dt = a0.x*b0.x + a0.y*b0.y + a0.z*b0.z + a0.w*b0.w
             + a1.x*b1.x + a1.y*b1.y + a1.z*b1.z + a1.w*b1.w;
    #pragma unroll
    for (int off = 32; off > 0; off >>= 1) {
        ss += __shfl_down(ss, off);
        dt += __shfl_down(dt, off);
    }
    __shared__ float red_ss[4], red_dt[4];
    __shared__ float s_rms;
    __shared__ int s_pos;
    const int wave = tid >> 6;
    if ((tid & 63) == 0) { red_ss[wave] = ss; red_dt[wave] = dt; }
    __syncthreads();
    if (tid == 0) {
        float S = red_ss[0] + red_ss[1] + red_ss[2] + red_ss[3];
        float D = red_dt[0] + red_dt[1] + red_dt[2] + red_dt[3];
        float prob = 1.0f / (1.0f + expf(-D));
        s_rms = 1.0f / sqrtf(S * (1.0f / (float)CDIM) + EPSV);
        int pos = -1;
        if (prob > 0.5f) {
            pos = atomicAdd(cnt, 1);
            idx[pos] = token;
            mv[pos] = (1.0f + prob) - prob;  // replicate STE mask_i rounding exactly
        }
        s_pos = pos;
    }
    __syncthreads();
    const float rms = s_rms;
    const int pos = s_pos;
    float* op = out + (size_t)token * CDIM;
    if (pos < 0) {
        // residual base only for unselected tokens
        f32x4 r0 = {a0.x, a0.y, a0.z, a0.w};
        f32x4 r1 = {a1.x, a1.y, a1.z, a1.w};
        __builtin_nontemporal_store(r0, (f32x4*)(op + tid * 8));
        __builtin_nontemporal_store(r1, (f32x4*)(op + tid * 8 + 4));
    } else {
        // packed-swizzled write: chunk t=tid of compacted row pos
        const int kt = tid >> 3, q8 = tid & 7;
        const int r = pos & 127, mi = pos >> 7;
        short8 o;
        o[0] = (short)f2bf(a0.x * rms); o[1] = (short)f2bf(a0.y * rms);
        o[2] = (short)f2bf(a0.z * rms); o[3] = (short)f2bf(a0.w * rms);
        o[4] = (short)f2bf(a1.x * rms); o[5] = (short)f2bf(a1.y * rms);
        o[6] = (short)f2bf(a1.z * rms); o[7] = (short)f2bf(a1.w * rms);
        size_t di = (((size_t)mi * 32 + kt) * 128 + r) * 64 + (size_t)((q8 ^ (r & 7)) << 3);
        __builtin_nontemporal_store(o, (short8*)(Xn + di));
    }
}

// C[m][n] = sum_k A[m][k]*B[n][k]; A,B in PACKED tile layout.
//
// ROUND-5 CHANGES (concurrency attack; K-loop semantics unchanged):
// * 8 waves (512 thr), wave grid 2Mx4N, wave tile 64x32: acc = 4x2 frags =
//   32 AGPR (was 64). __launch_bounds__(512,4) caps allocation at 128
//   regs/wave -> target 4 waves/SIMD (rounds 0-4 were stuck at ~5 waves/CU;
//   suspected 160-reg allocation quantum capping 2 waves/SIMD).
// * PERSISTENT grid: exactly 512 blocks (2/CU), each loops over live tiles
//   only (mp = ceil(cnt/128) read on-device) -> no dead blocks, no tail, no
//   refill imbalance.
// * XCD partition: block b serves XCD-slice (b&7); each XCD owns NP/8
//   n-panels, so its B-slice (4 MB GEMM1, 4 MB GEMM2) lives in its own L2.
// MODE 1: Hout = bf16(relu(acc)^2) in PACKED layout (GEMM2's A).
// MODE 2: out[token][n] = x[token][n] + scale*acc (each output owned once).
template <int K, int MODE, int LDO, int NP>
__global__ __launch_bounds__(512, 4) void gemm_bt(
    const unsigned short* __restrict__ A,
    const unsigned short* __restrict__ B,
    unsigned short* __restrict__ Hout,
    float* __restrict__ out,
    const float* __restrict__ xin,
    const int* __restrict__ idx,
    const float* __restrict__ mv,
    const int* __restrict__ cntp)
{
    const int cnt = *cntp;
    const int mp = (cnt + 127) >> 7;         // live m-panels
    const int xcd = blockIdx.x & 7;          // hw round-robins launch idx % 8
    const int wix = blockIdx.x >> 3;         // 0..63 within this XCD's crew
    constexpr int NPX = NP / 8;              // n-panels per XCD slice
    const int tiles_slice = mp * NPX;
    const int crew = (int)gridDim.x >> 3;    // blocks per XCD (64)

    const int tid = threadIdx.x;
    const int wave = tid >> 6;
    const int lane = tid & 63;
    const int wm = (wave >> 2) * 64;         // 2 wave-rows (M)
    const int wn = (wave & 3) * 32;          // 4 wave-cols (N)
    const int quad = lane >> 4;
    const int l16 = lane & 15;

    __shared__ alignas(16) unsigned short lA[128 * 64];
    __shared__ alignas(16) unsigned short lB[128 * 64];

    constexpr int PK = K / 64;
    constexpr int NT = K / 64;

    for (int t = wix; t < tiles_slice; t += crew) {
        const int mi = t % mp;
        const int ni = xcd * NPX + t / mp;
        const int m0 = mi * 128;
        const int n0 = ni * 128;

        // contiguous staging: thread tid covers 16B chunks tid and tid+512
        const unsigned short* aq = A + (size_t)mi * PK * 8192 + (size_t)tid * 8;
        const unsigned short* bq = B + (size_t)ni * PK * 8192 + (size_t)tid * 8;

        floatx4 acc[4][2] = {};

        for (int kt = 0; kt < NT; ++kt) {
            __builtin_amdgcn_global_load_lds(
                (__attribute__((address_space(1))) void*)aq,
                (__attribute__((address_space(3))) void*)&lA[(size_t)tid * 8],
                16, 0, 0);
            __builtin_amdgcn_global_load_lds(
                (__attribute__((address_space(1))) void*)(aq + 512 * 8),
                (__attribute__((address_space(3))) void*)&lA[((size_t)tid + 512) * 8],
                16, 0, 0);
            __builtin_amdgcn_global_load_lds(
                (__attribute__((address_space(1))) void*)bq,
                (__attribute__((address_space(3))) void*)&lB[(size_t)tid * 8],
                16, 0, 0);
            __builtin_amdgcn_global_load_lds(
                (__attribute__((address_space(1))) void*)(bq + 512 * 8),
                (__attribute__((address_space(3))) void*)&lB[((size_t)tid + 512) * 8],
                16, 0, 0);
            aq += 8192;
            bq += 8192;
            __syncthreads();  // drains vmcnt before LDS reads
            #pragma unroll
            for (int st = 0; st < 2; ++st) {
                frag_t af[4], bfv[2];
                #pragma unroll
                for (int tt = 0; tt < 4; ++tt) {
                    const int ra = wm + tt * 16 + l16;
                    const int ca = ((st * 4 + quad) ^ (ra & 7)) * 8;
                    af[tt] = *(const frag_t*)&lA[ra * 64 + ca];
                }
                #pragma unroll
                for (int tt = 0; tt < 2; ++tt) {
                    const int rb = wn + tt * 16 + l16;
                    const int cb = ((st * 4 + quad) ^ (rb & 7)) * 8;
                    bfv[tt] = *(const frag_t*)&lB[rb * 64 + cb];
                }
                #pragma unroll
                for (int tm = 0; tm < 4; ++tm)
                    #pragma unroll
                    for (int tn = 0; tn < 2; ++tn)
                        acc[tm][tn] = mfma_bf16(af[tm], bfv[tn], acc[tm][tn]);
            }
            __syncthreads();
        }

        // C/D layout (verified m89/m91): col(n) = lane&15, row(m) = quad*4+reg
        if (MODE == 1) {
            constexpr int PKH = LDO / 64;   // H packed with K = LDO = FDIM
            #pragma unroll
            for (int tm = 0; tm < 4; ++tm) {
                const int rbase = wm + tm * 16 + quad * 4;  // row within panel
                #pragma unroll
                for (int tn = 0; tn < 2; ++tn) {
                    const int gn = n0 + wn + tn * 16 + l16;
                    const int kt = gn >> 6, q8 = (gn >> 3) & 7, e = gn & 7;
                    #pragma unroll
                    for (int v = 0; v < 4; ++v) {
                        const int r = rbase + v;
                        float h = fmaxf(acc[tm][tn][v], 0.0f);  // eats NaN pads
                        size_t di = (((size_t)mi * PKH + kt) * 128 + r) * 64
                                  + (size_t)((q8 ^ (r & 7)) << 3) + e;
                        __builtin_nontemporal_store(f2bf(h * h), &Hout[di]);
                    }
                }
            }
        } else {
            #pragma unroll
            for (int tm = 0; tm < 4; ++tm) {
                const int gmb = m0 + wm + tm * 16 + quad * 4;
                #pragma unroll
                for (int v = 0; v < 4; ++v) {
                    const int gm = gmb + v;
                    if (gm < cnt) {  // never read poisoned idx/mv beyond cnt
                        const int token = idx[gm];
                        const float scale = mv[gm];
                        const float* xrow = xin + (size_t)token * LDO;
                        float* orow = out + (size_t)token * LDO;
                        #pragma unroll
                        for (int tn = 0; tn < 2; ++tn) {
                            const int gn = n0 + wn + tn * 16 + l16;
                            float r = xrow[gn] + scale * acc[tm][tn][v];
                            __builtin_nontemporal_store(r, &orow[gn]);
                        }
                    }
                }
            }
        }
    }
}

extern "C" void kernel_launch(void* const* d_in, const int* in_sizes, int n_in,
                              void* d_out, int out_size, void* d_ws, size_t ws_size,
                              hipStream_t stream)
{
    const float* x   = (const float*)d_in[0];
    const float* wfc = (const float*)d_in[1];
    const float* wpr = (const float*)d_in[2];
    const float* wrt = (const float*)d_in[3];
    float* out = (float*)d_out;

    // ws layout (bytes): [cnt 256][idx 32K][mv 32K][Xn 32M][Wfc 32M][Wpr 32M][H 128M]
    char* ws = (char*)d_ws;
    int*   cnt = (int*)ws;
    int*   idx = (int*)(ws + 256);
    float* mv  = (float*)(ws + 256 + 32768);
    unsigned short* Xn  = (unsigned short*)(ws + 65792);
    unsigned short* Wfc = (unsigned short*)(ws + 65792 + 33554432ULL);
    unsigned short* Wpr = (unsigned short*)(ws + 65792 + 67108864ULL);
    unsigned short* H   = (unsigned short*)(ws + 65792 + 100663296ULL);

    // chunks: Wfc FDIM*(CDIM/8) + Wpr CDIM*(FDIM/8) = 4,194,304 -> 16384 blocks
    const int nchunks = FDIM * (CDIM / 8) + CDIM * (FDIM / 8);
    zero_kernel<<<1, 64, 0, stream>>>(cnt);
    cvt2_kernel<<<nchunks / 256, 256, 0, stream>>>(wfc, Wfc, wpr, Wpr);
    router_kernel<<<TOKENS, 256, 0, stream>>>(x, wrt, out, Xn, idx, mv, cnt);
    // GEMM1: H[m][f] = relu(Xn @ Wfc^T)^2, M=cnt (<=8192), N=8192, K=2048
    gemm_bt<CDIM, 1, FDIM, FDIM / 128><<<512, 512, 0, stream>>>(
        Xn, Wfc, H, nullptr, nullptr, nullptr, nullptr, cnt);
    // GEMM2: out[token][c] = x[token][c] + mask_i*(H @ Wpr^T), M=cnt, N=2048, K=8192
    gemm_bt<FDIM, 2, CDIM, CDIM / 128><<<512, 512, 0, stream>>>(
        H, Wpr, nullptr, out, x, idx, mv, cnt);
}

// Round 6
// 698.057 us; speedup vs baseline: 1.0910x; 1.0720x over previous
//
#include <hip/hip_runtime.h>
#include <type_traits>
#include <utility>
#include <stdint.h>
#include <stddef.h>

#define TOKENS 8192
#define CDIM 2048
#define FDIM 8192
#define EPSV 1.1920929e-07f

typedef __attribute__((ext_vector_type(8))) short short8;
typedef __attribute__((ext_vector_type(8))) __bf16 bf16x8;
typedef __attribute__((ext_vector_type(4))) float floatx4;
typedef __attribute__((ext_vector_type(4))) float f32x4;
typedef __attribute__((ext_vector_type(2))) unsigned int u32x2;

// Detect which operand typing this clang uses for the gfx950 bf16 MFMA builtin.
template <typename V, typename = void> struct CanMfma : std::false_type {};
template <typename V>
struct CanMfma<V, std::void_t<decltype(__builtin_amdgcn_mfma_f32_16x16x32_bf16(
    std::declval<V>(), std::declval<V>(), std::declval<floatx4>(), 0, 0, 0))>>
    : std::true_type {};
using frag_t = std::conditional_t<CanMfma<short8>::value, short8, bf16x8>;

__device__ __forceinline__ floatx4 mfma_bf16(frag_t a, frag_t b, floatx4 c) {
    return __builtin_amdgcn_mfma_f32_16x16x32_bf16(a, b, c, 0, 0, 0);
}

// round-to-nearest-even f32 -> bf16
__device__ __forceinline__ unsigned short f2bf(float f) {
    unsigned int u = __float_as_uint(f);
    u += 0x7fffu + ((u >> 16) & 1u);
    return (unsigned short)(u >> 16);
}

__global__ void zero_kernel(int* p) { if (threadIdx.x == 0) *p = 0; }

// ---------------------------------------------------------------------------
// PACKED TILE LAYOUT (kept from round 4): operands stored as
// [panel(128 rows)][ktile(64 cols)] 16 KB contiguous tile-chunks, XOR chunk
// swizzle baked in:
//   element (row=n, k) -> u16 index
//     ((n>>7)*PK + (k>>6))*8192 + ((n&127)*8 + (((k>>3)&7) ^ (n&7)))*8 + (k&7)
// GEMM staging reads each tile as one contiguous 16 KB stream.
// ---------------------------------------------------------------------------

// Convert both weight matrices fp32 -> packed-swizzled bf16 in one launch.
// Wfc: rows=FDIM, K=CDIM (PK=32). Wpr: rows=CDIM, K=FDIM (PK=128).
__global__ __launch_bounds__(256) void cvt2_kernel(
    const float* __restrict__ s1, unsigned short* __restrict__ d1,
    const float* __restrict__ s2, unsigned short* __restrict__ d2)
{
    const int NC1 = FDIM * (CDIM / 8);   // 16B chunks in matrix 1
    int i = blockIdx.x * 256 + threadIdx.x;
    const float* src; unsigned short* dst;
    int n, t, PK, K8;
    if (i < NC1) { src = s1; dst = d1; n = i >> 8; t = i & 255; PK = 32; K8 = 256; }
    else { i -= NC1; src = s2; dst = d2; n = i >> 10; t = i & 1023; PK = 128; K8 = 1024; }
    const int kt = t >> 3, q8 = t & 7;
    const int r = n & 127, ni = n >> 7;
    const float4* sp = (const float4*)src + ((size_t)n * K8 + t) * 2;
    float4 v0 = sp[0], v1 = sp[1];
    short8 o;
    o[0] = (short)f2bf(v0.x); o[1] = (short)f2bf(v0.y);
    o[2] = (short)f2bf(v0.z); o[3] = (short)f2bf(v0.w);
    o[4] = (short)f2bf(v1.x); o[5] = (short)f2bf(v1.y);
    o[6] = (short)f2bf(v1.z); o[7] = (short)f2bf(v1.w);
    size_t di = (((size_t)ni * PK + kt) * 128 + r) * 64 + (size_t)((q8 ^ (r & 7)) << 3);
    __builtin_nontemporal_store(o, (short8*)(dst + di));
}

// Per token: router logit, sigmoid mask, RMSNorm; compact selected tokens into
// Xn (bf16, PACKED layout, PK=32). UNSELECTED tokens get out = x here;
// SELECTED tokens are fully written by GEMM2 (out = x + mask*mlp).
__global__ __launch_bounds__(256) void router_kernel(
    const float* __restrict__ x, const float* __restrict__ wr,
    float* __restrict__ out, unsigned short* __restrict__ Xn,
    int* __restrict__ idx, float* __restrict__ mv, int* __restrict__ cnt)
{
    const int token = blockIdx.x;
    const int tid = threadIdx.x;
    const float4* xr = (const float4*)(x + (size_t)token * CDIM);
    const float4* w4 = (const float4*)wr;
    // thread tid owns k = tid*8 .. tid*8+7  (one packed 16B chunk)
    float4 a0 = xr[2 * tid];
    float4 a1 = xr[2 * tid + 1];
    float4 b0 = w4[2 * tid];
    float4 b1 = w4[2 * tid + 1];
    float ss = a0.x*a0.x + a0.y*a0.y + a0.z*a0.z + a0.w*a0.w
             + a1.x*a1.x + a1.y*a1.y + a1.z*a1.z + a1.w*a1.w;
    float dt = a0.x*b0.x + a0.y*b0.y + a0.z*b0.z + a0.w*b0.w
             + a1.x*b1.x + a1.y*b1.y + a1.z*b1.z + a1.w*b1.w;
    #pragma unroll
    for (int off = 32; off > 0; off >>= 1) {
        ss += __shfl_down(ss, off);
        dt += __shfl_down(dt, off);
    }
    __shared__ float red_ss[4], red_dt[4];
    __shared__ float s_rms;
    __shared__ int s_pos;
    const int wave = tid >> 6;
    if ((tid & 63) == 0) { red_ss[wave] = ss; red_dt[wave] = dt; }
    __syncthreads();
    if (tid == 0) {
        float S = red_ss[0] + red_ss[1] + red_ss[2] + red_ss[3];
        float D = red_dt[0] + red_dt[1] + red_dt[2] + red_dt[3];
        float prob = 1.0f / (1.0f + expf(-D));
        s_rms = 1.0f / sqrtf(S * (1.0f / (float)CDIM) + EPSV);
        int pos = -1;
        if (prob > 0.5f) {
            pos = atomicAdd(cnt, 1);
            idx[pos] = token;
            mv[pos] = (1.0f + prob) - prob;  // replicate STE mask_i rounding exactly
        }
        s_pos = pos;
    }
    __syncthreads();
    const float rms = s_rms;
    const int pos = s_pos;
    float* op = out + (size_t)token * CDIM;
    if (pos < 0) {
        // residual base only for unselected tokens
        f32x4 r0 = {a0.x, a0.y, a0.z, a0.w};
        f32x4 r1 = {a1.x, a1.y, a1.z, a1.w};
        __builtin_nontemporal_store(r0, (f32x4*)(op + tid * 8));
        __builtin_nontemporal_store(r1, (f32x4*)(op + tid * 8 + 4));
    } else {
        // packed-swizzled write: chunk t=tid of compacted row pos
        const int kt = tid >> 3, q8 = tid & 7;
        const int r = pos & 127, mi = pos >> 7;
        short8 o;
        o[0] = (short)f2bf(a0.x * rms); o[1] = (short)f2bf(a0.y * rms);
        o[2] = (short)f2bf(a0.z * rms); o[3] = (short)f2bf(a0.w * rms);
        o[4] = (short)f2bf(a1.x * rms); o[5] = (short)f2bf(a1.y * rms);
        o[6] = (short)f2bf(a1.z * rms); o[7] = (short)f2bf(a1.w * rms);
        size_t di = (((size_t)mi * 32 + kt) * 128 + r) * 64 + (size_t)((q8 ^ (r & 7)) << 3);
        __builtin_nontemporal_store(o, (short8*)(Xn + di));
    }
}

// C[m][n] = sum_k A[m][k]*B[n][k]; A,B in PACKED tile layout.
//
// ROUND-6 CHANGE (one variable): staging mechanism global_load_lds ->
// REG-STAGED 2-deep cross-barrier pipeline (T14). Hypothesis from rounds
// 0-5: the LDS-direct load path caps outstanding requests (rounds with 0, 4,
// and 12 nominal in-flight gld-lds all staged at the same ~6.7 TB/s;
// reference m103, warm, stages 13.6 TB/s with the same structure). Regular
// global_load_dwordx4 -> VGPR -> ds_write_b128 supports deep queues.
//
// Iteration kt (lds[tile&1] holds tile; set parity = tile parity):
//   issue 8 global loads (tile kt+2) -> free reg set   [stay in flight]
//   ds_write reg set (tile kt+1) -> lds[(kt+1)&1]      [compiler emits
//        counted vmcnt: waits only the 8 OLDER loads, newest 8 keep flying]
//   compute lds[kt&1]  (ds_read frags + 16 MFMA/wave)
//   s_waitcnt lgkmcnt(0); raw s_barrier                [NO vmcnt drain ever]
// Safety: each LDS overwrite targets the buffer whose readers all passed the
// previous barrier; loads never cross into LDS without an lgkm-drained write.
//
// Persistent grid (r5): 512 blocks, XCD-sliced n-panels, live tiles only.
// MODE 1: Hout = bf16(relu(acc)^2) in PACKED layout (GEMM2's A).
// MODE 2: out[token][n] = x[token][n] + scale*acc (each output owned once).
template <int K, int MODE, int LDO, int NP>
__global__ __launch_bounds__(512, 4) void gemm_bt(
    const unsigned short* __restrict__ A,
    const unsigned short* __restrict__ B,
    unsigned short* __restrict__ Hout,
    float* __restrict__ out,
    const float* __restrict__ xin,
    const int* __restrict__ idx,
    const float* __restrict__ mv,
    const int* __restrict__ cntp)
{
    const int cnt = *cntp;
    const int mp = (cnt + 127) >> 7;         // live m-panels
    const int xcd = blockIdx.x & 7;          // hw round-robins launch idx % 8
    const int wix = blockIdx.x >> 3;         // 0..63 within this XCD's crew
    constexpr int NPX = NP / 8;              // n-panels per XCD slice
    const int tiles_slice = mp * NPX;
    const int crew = (int)gridDim.x >> 3;    // blocks per XCD (64)

    const int tid = threadIdx.x;
    const int wave = tid >> 6;
    const int lane = tid & 63;
    const int wm = (wave >> 2) * 64;         // 2 wave-rows (M)
    const int wn = (wave & 3) * 32;          // 4 wave-cols (N)
    const int quad = lane >> 4;
    const int l16 = lane & 15;

    __shared__ alignas(16) unsigned short lA[2][128 * 64];
    __shared__ alignas(16) unsigned short lB[2][128 * 64];

    constexpr int PK = K / 64;
    constexpr int NT = K / 64;
    static_assert(NT % 2 == 0, "NT must be even");

    const size_t c0 = (size_t)tid * 8;
    const size_t c1 = (size_t)(tid + 512) * 8;

    for (int t = wix; t < tiles_slice; t += crew) {
        const int mi = t % mp;
        const int ni = xcd * NPX + t / mp;
        const int m0 = mi * 128;
        const int n0 = ni * 128;

        const unsigned short* aq = A + (size_t)mi * PK * 8192;
        const unsigned short* bq = B + (size_t)ni * PK * 8192;

        short8 a0_0, a1_0, b0_0, b1_0;   // reg set 0 (even tiles)
        short8 a0_1, a1_1, b0_1, b1_1;   // reg set 1 (odd tiles)

        // prologue: tile0 -> set0 -> lds[0]; tile1 -> set1 (left in flight)
        a0_0 = *(const short8*)(aq + c0);  a1_0 = *(const short8*)(aq + c1);
        b0_0 = *(const short8*)(bq + c0);  b1_0 = *(const short8*)(bq + c1);
        a0_1 = *(const short8*)(aq + 8192 + c0);  a1_1 = *(const short8*)(aq + 8192 + c1);
        b0_1 = *(const short8*)(bq + 8192 + c0);  b1_1 = *(const short8*)(bq + 8192 + c1);
        *(short8*)&lA[0][c0] = a0_0;  *(short8*)&lA[0][c1] = a1_0;
        *(short8*)&lB[0][c0] = b0_0;  *(short8*)&lB[0][c1] = b1_0;
        asm volatile("s_waitcnt lgkmcnt(0)" ::: "memory");
        __builtin_amdgcn_s_barrier();
        asm volatile("" ::: "memory");

        floatx4 acc[4][2] = {};

        auto compute = [&](int buf) {
            #pragma unroll
            for (int st = 0; st < 2; ++st) {
                frag_t af[4], bfv[2];
                #pragma unroll
                for (int tt = 0; tt < 4; ++tt) {
                    const int ra = wm + tt * 16 + l16;
                    const int ca = ((st * 4 + quad) ^ (ra & 7)) * 8;
                    af[tt] = *(const frag_t*)&lA[buf][ra * 64 + ca];
                }
                #pragma unroll
                for (int tt = 0; tt < 2; ++tt) {
                    const int rb = wn + tt * 16 + l16;
                    const int cb = ((st * 4 + quad) ^ (rb & 7)) * 8;
                    bfv[tt] = *(const frag_t*)&lB[buf][rb * 64 + cb];
                }
                #pragma unroll
                for (int tm = 0; tm < 4; ++tm)
                    #pragma unroll
                    for (int tn = 0; tn < 2; ++tn)
                        acc[tm][tn] = mfma_bf16(af[tm], bfv[tn], acc[tm][tn]);
            }
        };

        for (int kt = 0; kt < NT; kt += 2) {
            // ---- even body: compute tile kt (lds[0]); set1 -> lds[1]; set0 <- kt+2
            if (kt + 2 < NT) {
                const unsigned short* a = aq + (size_t)(kt + 2) * 8192;
                const unsigned short* b = bq + (size_t)(kt + 2) * 8192;
                a0_0 = *(const short8*)(a + c0);  a1_0 = *(const short8*)(a + c1);
                b0_0 = *(const short8*)(b + c0);  b1_0 = *(const short8*)(b + c1);
            }
            *(short8*)&lA[1][c0] = a0_1;  *(short8*)&lA[1][c1] = a1_1;
            *(short8*)&lB[1][c0] = b0_1;  *(short8*)&lB[1][c1] = b1_1;
            compute(0);
            asm volatile("s_waitcnt lgkmcnt(0)" ::: "memory");
            __builtin_amdgcn_s_barrier();
            asm volatile("" ::: "memory");

            // ---- odd body: compute tile kt+1 (lds[1]); set0 -> lds[0]; set1 <- kt+3
            if (kt + 3 < NT) {
                const unsigned short* a = aq + (size_t)(kt + 3) * 8192;
                const unsigned short* b = bq + (size_t)(kt + 3) * 8192;
                a0_1 = *(const short8*)(a + c0);  a1_1 = *(const short8*)(a + c1);
                b0_1 = *(const short8*)(b + c0);  b1_1 = *(const short8*)(b + c1);
            }
            if (kt + 2 < NT) {
                *(short8*)&lA[0][c0] = a0_0;  *(short8*)&lA[0][c1] = a1_0;
                *(short8*)&lB[0][c0] = b0_0;  *(short8*)&lB[0][c1] = b1_0;
            }
            compute(1);
            asm volatile("s_waitcnt lgkmcnt(0)" ::: "memory");
            __builtin_amdgcn_s_barrier();
            asm volatile("" ::: "memory");
        }

        // C/D layout (verified m89/m91): col(n) = lane&15, row(m) = quad*4+reg
        if (MODE == 1) {
            constexpr int PKH = LDO / 64;   // H packed with K = LDO = FDIM
            #pragma unroll
            for (int tm = 0; tm < 4; ++tm) {
                const int rbase = wm + tm * 16 + quad * 4;  // row within panel
                #pragma unroll
                for (int tn = 0; tn < 2; ++tn) {
                    const int gn = n0 + wn + tn * 16 + l16;
                    const int kt = gn >> 6, q8 = (gn >> 3) & 7, e = gn & 7;
                    #pragma unroll
                    for (int v = 0; v < 4; ++v) {
                        const int r = rbase + v;
                        float h = fmaxf(acc[tm][tn][v], 0.0f);  // eats NaN pads
                        size_t di = (((size_t)mi * PKH + kt) * 128 + r) * 64
                                  + (size_t)((q8 ^ (r & 7)) << 3) + e;
                        __builtin_nontemporal_store(f2bf(h * h), &Hout[di]);
                    }
                }
            }
        } else {
            #pragma unroll
            for (int tm = 0; tm < 4; ++tm) {
                const int gmb = m0 + wm + tm * 16 + quad * 4;
                #pragma unroll
                for (int v = 0; v < 4; ++v) {
                    const int gm = gmb + v;
                    if (gm < cnt) {  // never read poisoned idx/mv beyond cnt
                        const int token = idx[gm];
                        const float scale = mv[gm];
                        const float* xrow = xin + (size_t)token * LDO;
                        float* orow = out + (size_t)token * LDO;
                        #pragma unroll
                        for (int tn = 0; tn < 2; ++tn) {
                            const int gn = n0 + wn + tn * 16 + l16;
                            float r = xrow[gn] + scale * acc[tm][tn][v];
                            __builtin_nontemporal_store(r, &orow[gn]);
                        }
                    }
                }
            }
        }
    }
}

extern "C" void kernel_launch(void* const* d_in, const int* in_sizes, int n_in,
                              void* d_out, int out_size, void* d_ws, size_t ws_size,
                              hipStream_t stream)
{
    const float* x   = (const float*)d_in[0];
    const float* wfc = (const float*)d_in[1];
    const float* wpr = (const float*)d_in[2];
    const float* wrt = (const float*)d_in[3];
    float* out = (float*)d_out;

    // ws layout (bytes): [cnt 256][idx 32K][mv 32K][Xn 32M][Wfc 32M][Wpr 32M][H 128M]
    char* ws = (char*)d_ws;
    int*   cnt = (int*)ws;
    int*   idx = (int*)(ws + 256);
    float* mv  = (float*)(ws + 256 + 32768);
    unsigned short* Xn  = (unsigned short*)(ws + 65792);
    unsigned short* Wfc = (unsigned short*)(ws + 65792 + 33554432ULL);
    unsigned short* Wpr = (unsigned short*)(ws + 65792 + 67108864ULL);
    unsigned short* H   = (unsigned short*)(ws + 65792 + 100663296ULL);

    // chunks: Wfc FDIM*(CDIM/8) + Wpr CDIM*(FDIM/8) = 4,194,304 -> 16384 blocks
    const int nchunks = FDIM * (CDIM / 8) + CDIM * (FDIM / 8);
    zero_kernel<<<1, 64, 0, stream>>>(cnt);
    cvt2_kernel<<<nchunks / 256, 256, 0, stream>>>(wfc, Wfc, wpr, Wpr);
    router_kernel<<<TOKENS, 256, 0, stream>>>(x, wrt, out, Xn, idx, mv, cnt);
    // GEMM1: H[m][f] = relu(Xn @ Wfc^T)^2, M=cnt (<=8192), N=8192, K=2048
    gemm_bt<CDIM, 1, FDIM, FDIM / 128><<<512, 512, 0, stream>>>(
        Xn, Wfc, H, nullptr, nullptr, nullptr, nullptr, cnt);
    // GEMM2: out[token][c] = x[token][c] + mask_i*(H @ Wpr^T), M=cnt, N=2048, K=8192
    gemm_bt<FDIM, 2, CDIM, CDIM / 128><<<512, 512, 0, stream>>>(
        H, Wpr, nullptr, out, x, idx, mv, cnt);
}